// Round 1
// baseline (172.992 us; speedup 1.0000x reference)
//
#include <hip/hip_runtime.h>

// ---------- fused kernel: per-block range scan + grouped GEMM, NO workspace ----------
// Replaces {memset, bucket_k, fge_gemm} + global bucket arrays (which forced the harness
// to poison a ~410 MB workspace inside the timed window at ~61 us per 400 MB fill).
//
// Decomposition: grid (NR range-blocks, 4 z-tiles, 8 partitions). Each block scans its
// RANGE=384 token indices (coalesced x read, L2-resident parts gather), compacts tokens
// of its partition into an LDS list (E[n]=48, P(n>64)~0.5%), then runs the proven
// LDS-slab GEMM: W slab [x][z] staged once, E chunks of KC=32, per lane 4 tok x 4 z.
#define KC 32
#define RANGE 384

__global__ __launch_bounds__(256)
void fge_fused(const int* __restrict__ x,
               const float* __restrict__ emb,
               const float* __restrict__ weight,
               const int* __restrict__ parts,
               float* __restrict__ out, int NT) {
    const int p   = blockIdx.z;
    const int z0  = blockIdx.y * 64;
    const int s0  = blockIdx.x * RANGE;
    if (s0 >= NT) return;
    const int r   = min(RANGE, NT - s0);
    const int K   = 256 >> p;                       // active input dim
    const int tid = threadIdx.x;

    __shared__ __align__(16) float w_lds[256][64];  // [x][z]  64 KB
    __shared__ __align__(16) float e_lds[KC][64];   // [x][tok] 8 KB
    __shared__ int toklist[RANGE];                  // token index (for output addr)
    __shared__ int rowlist[RANGE];                  // emb row (x[i]), avoids re-gather
    __shared__ int nloc;

    if (tid == 0) nloc = 0;
    __syncthreads();

    // ---- phase 1: scan range, compact matching tokens (LDS atomic: cheap) ----
    for (int t = tid; t < r; t += 256) {
        const int i   = s0 + t;
        const int row = x[i];                        // coalesced
        if (parts[row] == p) {                       // L2-resident 400 KB table
            const int pos = atomicAdd(&nloc, 1);
            toklist[pos] = i;
            rowlist[pos] = row;
        }
    }

    // ---- phase 1b (overlapped): stage W slab once (x-major; zero-pad x in [K,32)) ----
    {
        const int Kpad = (K < KC) ? KC : K;          // compute only reads x < max(K,32)
        const int wrow = tid >> 2;                   // z row 0..63
        const float* wbase = weight + ((size_t)p * 256 + (z0 + wrow)) * 256;
        for (int colb = (tid & 3) * 4; colb < Kpad; colb += 16) {
            float4 v = *(const float4*)(wbase + colb);   // 64B-coalesced per 4 lanes
            float vv[4] = {v.x, v.y, v.z, v.w};
#pragma unroll
            for (int c = 0; c < 4; ++c)
                w_lds[colb + c][wrow] = (colb + c < K) ? vv[c] : 0.f;
        }
    }
    __syncthreads();                                 // lists + W slab visible

    const int n = nloc;                              // block-uniform
    if (n == 0) return;

    const int tz  = tid & 15;     // z-group: owns z0 + tz*4 .. +3 (coalesced stores)
    const int tt  = tid >> 4;     // token-group: owns tokens tt*4 .. +3
    const int t_l = tid & 63;     // staging: token slot
    const int xh  = tid >> 6;     // staging: x sub-range xh*8 .. +7
    const int nch = (K + KC - 1) / KC;

    for (int t0 = 0; t0 < n; t0 += 64) {             // almost always exactly one tile
        const int ntile = min(64, n - t0);
        float acc[4][4] = {};

        for (int ch = 0; ch < nch; ++ch) {
            // ---- stage E chunk (zero-fill beyond K / beyond ntile) ----
            {
                const bool tv  = (t_l < ntile);
                const int  row = tv ? rowlist[t0 + t_l] : rowlist[0];
                const float* er = emb + (size_t)row * 256;
                const int gxb = ch * KC + xh * 8;
                float4 a = *(const float4*)(er + gxb);       // always in-bounds (<256)
                float4 b = *(const float4*)(er + gxb + 4);
                float va[8] = {a.x, a.y, a.z, a.w, b.x, b.y, b.z, b.w};
#pragma unroll
                for (int c = 0; c < 8; ++c) {
                    int gx = gxb + c;
                    e_lds[xh * 8 + c][t_l] = (tv && gx < K) ? va[c] : 0.f;
                }
            }
            __syncthreads();

            // ---- compute: 32 x-steps, 2 ds_read_b128 + 16 FMA each ----
#pragma unroll
            for (int c = 0; c < KC; ++c) {
                const float4 ev = *(const float4*)&e_lds[c][tt * 4];
                const float4 wv = *(const float4*)&w_lds[ch * KC + c][tz * 4];
                const float ea[4] = {ev.x, ev.y, ev.z, ev.w};
                const float wa[4] = {wv.x, wv.y, wv.z, wv.w};
#pragma unroll
                for (int i = 0; i < 4; ++i)
#pragma unroll
                    for (int j = 0; j < 4; ++j)
                        acc[i][j] = fmaf(ea[i], wa[j], acc[i][j]);
            }
            __syncthreads();      // before next chunk overwrites e_lds
        }

        // ---- epilogue: float4 stores, 16 lanes cover one token row's 64 z ----
#pragma unroll
        for (int i = 0; i < 4; ++i) {
            const int t = tt * 4 + i;
            if (t < ntile) {
                float4 o = {acc[i][0], acc[i][1], acc[i][2], acc[i][3]};
                *(float4*)(out + (size_t)toklist[t0 + t] * 256 + z0 + tz * 4) = o;
            }
        }
    }
}

// ---------- generic fallback (any D/P) ----------
__global__ void naive_k(const int* __restrict__ x, const float* __restrict__ emb,
                        const float* __restrict__ w, const int* __restrict__ parts,
                        float* __restrict__ out, int D, int P) {
    const int i = blockIdx.x;
    const int tokrow = x[i];
    const int p = parts[tokrow];
    const int K = D >> p;
    const float* er = emb + (size_t)tokrow * D;
    for (int z = threadIdx.x; z < D; z += blockDim.x) {
        const float* wr = w + ((size_t)p * D + z) * D;
        float acc = 0.f;
        for (int k = 0; k < K; ++k) acc = fmaf(er[k], wr[k], acc);
        out[(size_t)i * D + z] = acc;
    }
}

extern "C" void kernel_launch(void* const* d_in, const int* in_sizes, int n_in,
                              void* d_out, int out_size, void* d_ws, size_t ws_size,
                              hipStream_t stream) {
    const int*   xi    = (const int*)d_in[0];
    const float* emb   = (const float*)d_in[1];
    const float* wgt   = (const float*)d_in[2];
    const int*   parts = (const int*)d_in[3];
    float* out = (float*)d_out;

    const int NT = in_sizes[0];
    const long long V = in_sizes[3];
    const int D = (int)(in_sizes[1] / V);
    const int P = (int)(in_sizes[2] / ((long long)D * D));

    if (D == 256 && P == 8) {
        // Single dispatch, zero workspace use.
        const int NR = (NT + RANGE - 1) / RANGE;
        dim3 grid(NR, 4, 8);
        fge_fused<<<grid, 256, 0, stream>>>(xi, emb, wgt, parts, out, NT);
    } else {
        naive_k<<<NT, 256, 0, stream>>>(xi, emb, wgt, parts, out, D, P);
    }
}

// Round 2
// 163.538 us; speedup vs baseline: 1.0578x; 1.0578x over previous
//
#include <hip/hip_runtime.h>

// ---------- kernel 1: per-scan-block partition segments ----------
// NO global atomics, NO memset prerequisite: every workspace word the GEMM reads
// (cnt, and segs entries < cnt) is written here first. Poisoned ws never read.
// Block b scans tokens [b*256, b*256+256); token i with partition p lands at
// segs[p][b][pos] (stride 256 => overflow impossible even if all 256 match).
__global__ void bucket_seg(const int* __restrict__ x, const int* __restrict__ parts,
                           int* __restrict__ cnt, int* __restrict__ segs,
                           int NT, int NB) {
    __shared__ int lcnt[8];
    const int tid = threadIdx.x;
    const int b = blockIdx.x;
    if (tid < 8) lcnt[tid] = 0;
    __syncthreads();
    const int i = b * 256 + tid;
    if (i < NT) {
        const int row = x[i];
        const int p = parts[row];                    // L2-resident 400 KB table
        const int pos = atomicAdd(&lcnt[p], 1);      // LDS atomic: cheap
        segs[((size_t)p * NB + b) * 256 + pos] = i;
    }
    __syncthreads();
    if (tid < 8) cnt[tid * NB + b] = lcnt[tid];
}

// ---------- kernel 2: grouped GEMM per partition (fp32) ----------
// Proven R0 core (162.5 us), unchanged except the token-list source:
// counts -> 6-step LDS prefix scan -> per-slot binary search into segments.
// Tiles stay 100% dense (the fused R1 variant's 75% density cost ~10 us).
#define KC 32
#define XB 32

__global__ __launch_bounds__(256)
void fge_gemm(const int* __restrict__ x,
              const float* __restrict__ emb,
              const float* __restrict__ weight,
              const int* __restrict__ cnt,
              const int* __restrict__ segs,
              float* __restrict__ out, int NB) {
    const int p   = blockIdx.z;
    const int z0  = blockIdx.y * 64;
    const int K   = 256 >> p;                       // active input dim
    const int tid = threadIdx.x;

    __shared__ __align__(16) float w_lds[256][64];  // [x][z]  64 KB
    __shared__ __align__(16) float e_lds[KC][64];   // [x][tok] 8 KB
    __shared__ int pfx[65];
    __shared__ int vrow[64];
    __shared__ int oidx[64];

    // ---- prologue: counts -> inclusive prefix (NB <= 64; zero-pad) ----
    {
        __shared__ int ctmp[64];
        if (tid < 64) ctmp[tid] = (tid < NB) ? cnt[p * NB + tid] : 0;
        __syncthreads();
        for (int d = 1; d < 64; d <<= 1) {
            int v = 0;
            if (tid < 64) v = ctmp[tid] + ((tid >= d) ? ctmp[tid - d] : 0);
            __syncthreads();
            if (tid < 64) ctmp[tid] = v;
            __syncthreads();
        }
        if (tid < 64) pfx[tid + 1] = ctmp[tid];
        if (tid == 0) pfx[0] = 0;
        __syncthreads();
    }
    const int n = pfx[64];
    if ((int)(blockIdx.x * 64) >= n) return;        // block-uniform early exit

    // ---- stage W slab once (x-major transpose; zero-pad x in [K, 32)) ----
    {
        const int Kpad = (K < KC) ? KC : K;         // compute only ever reads x < max(K,32)
        const int wrow = tid >> 2;                  // z row 0..63
        const float* wbase = weight + ((size_t)p * 256 + (z0 + wrow)) * 256;
        for (int colb = (tid & 3) * 4; colb < Kpad; colb += 16) {
            float4 v = *(const float4*)(wbase + colb);   // 64B-coalesced per 4 lanes
            float vv[4] = {v.x, v.y, v.z, v.w};
#pragma unroll
            for (int c = 0; c < 4; ++c)
                w_lds[colb + c][wrow] = (colb + c < K) ? vv[c] : 0.f;
        }
    }

    const int tz  = tid & 15;     // z-group: owns z0 + tz*4 .. +3  (coalesced stores)
    const int tt  = tid >> 4;     // token-group: owns tokens tt*4 .. +3
    const int t_l = tid & 63;     // staging: token slot
    const int xh  = tid >> 6;     // staging: x sub-range xh*8 .. +7
    const int nch = (K + KC - 1) / KC;

    for (int t0 = blockIdx.x * 64; t0 < n; t0 += XB * 64) {
        const int ntile = min(64, n - t0);

        __syncthreads();          // W slab + pfx visible (iter 0); oidx safe (iter >0)
        if (tid < 64) {
            int idx = 0, row = 0;
            if (t_l < ntile) {
                const int s = t0 + t_l;
                int b = 0;        // max b with pfx[b] <= s  (monotone; ties -> larger b)
#pragma unroll
                for (int st = 32; st; st >>= 1)
                    if (pfx[b + st] <= s) b += st;
                const int off = s - pfx[b];
                idx = segs[((size_t)p * NB + b) * 256 + off];
                row = x[idx];
            }
            oidx[t_l] = idx;
            vrow[t_l] = row;
        }
        __syncthreads();          // vrow visible to all stagers

        float acc[4][4] = {};

        for (int ch = 0; ch < nch; ++ch) {
            // ---- stage E chunk (zero-fill beyond K / beyond ntile) ----
            {
                const bool tv = (t_l < ntile);
                const float* er = emb + (size_t)vrow[t_l] * 256;
                const int gxb = ch * KC + xh * 8;
                float4 a = *(const float4*)(er + gxb);       // always in-bounds
                float4 b4 = *(const float4*)(er + gxb + 4);
                float va[8] = {a.x, a.y, a.z, a.w, b4.x, b4.y, b4.z, b4.w};
#pragma unroll
                for (int c = 0; c < 8; ++c) {
                    int gx = gxb + c;
                    e_lds[xh * 8 + c][t_l] = (tv && gx < K) ? va[c] : 0.f;
                }
            }
            __syncthreads();

            // ---- compute: 32 x-steps, 2 ds_read_b128 + 16 FMA each ----
#pragma unroll
            for (int c = 0; c < KC; ++c) {
                const float4 ev = *(const float4*)&e_lds[c][tt * 4];
                const float4 wv = *(const float4*)&w_lds[ch * KC + c][tz * 4];
                const float ea[4] = {ev.x, ev.y, ev.z, ev.w};
                const float wa[4] = {wv.x, wv.y, wv.z, wv.w};
#pragma unroll
                for (int i = 0; i < 4; ++i)
#pragma unroll
                    for (int j = 0; j < 4; ++j)
                        acc[i][j] = fmaf(ea[i], wa[j], acc[i][j]);
            }
            __syncthreads();      // before next chunk overwrites e_lds
        }

        // ---- epilogue: float4 stores, 16 lanes cover one token row's 64 z ----
#pragma unroll
        for (int i = 0; i < 4; ++i) {
            const int t = tt * 4 + i;
            if (t < ntile) {
                float4 o = {acc[i][0], acc[i][1], acc[i][2], acc[i][3]};
                *(float4*)(out + (size_t)oidx[t] * 256 + z0 + tz * 4) = o;
            }
        }
    }
}

// ---------- generic fallback (any D/P, or ws too small / NT too large) ----------
__global__ void naive_k(const int* __restrict__ x, const float* __restrict__ emb,
                        const float* __restrict__ w, const int* __restrict__ parts,
                        float* __restrict__ out, int D, int P) {
    const int i = blockIdx.x;
    const int tokrow = x[i];
    const int p = parts[tokrow];
    const int K = D >> p;
    const float* er = emb + (size_t)tokrow * D;
    for (int z = threadIdx.x; z < D; z += blockDim.x) {
        const float* wr = w + ((size_t)p * D + z) * D;
        float acc = 0.f;
        for (int k = 0; k < K; ++k) acc = fmaf(er[k], wr[k], acc);
        out[(size_t)i * D + z] = acc;
    }
}

extern "C" void kernel_launch(void* const* d_in, const int* in_sizes, int n_in,
                              void* d_out, int out_size, void* d_ws, size_t ws_size,
                              hipStream_t stream) {
    const int*   xi    = (const int*)d_in[0];
    const float* emb   = (const float*)d_in[1];
    const float* wgt   = (const float*)d_in[2];
    const int*   parts = (const int*)d_in[3];
    float* out = (float*)d_out;

    const int NT = in_sizes[0];
    const long long V = in_sizes[3];
    const int D = (int)(in_sizes[1] / V);
    const int P = (int)(in_sizes[2] / ((long long)D * D));

    const int NB = (NT + 255) / 256;
    const size_t need = (size_t)8 * NB * 4            // cnt[8][NB]
                      + (size_t)8 * NB * 256 * 4;     // segs[8][NB][256]

    if (D == 256 && P == 8 && NB <= 64 && ws_size >= need) {
        int* cnt  = (int*)d_ws;
        int* segs = (int*)((char*)d_ws + (size_t)8 * NB * 4);
        bucket_seg<<<NB, 256, 0, stream>>>(xi, parts, cnt, segs, NT, NB);
        dim3 grid(XB, 4, 8);
        fge_gemm<<<grid, 256, 0, stream>>>(xi, emb, wgt, cnt, segs, out, NB);
    } else {
        naive_k<<<NT, 256, 0, stream>>>(xi, emb, wgt, parts, out, D, P);
    }
}